// Round 25
// baseline (3675.906 us; speedup 1.0000x reference)
//
#include <hip/hip_runtime.h>

// SNN-MNIST forward + STDP, MI355X persistent cooperative kernel.
// Round 29: R25/R28 base (3540 us PASS) with ONE zero-numerics change:
// the epoch-end barrier is split across the loop boundary. Loop-end:
// drain + publish fsy2=t+1 ONLY. Loop-start: issue block-private prelude
// (sppo own-row load, syn/mem loads, wave-7 list build on read-only img)
// BEFORE polling fsy2 >= t, then sync, then the Wt-dependent gather.
// The epoch straggler wait now overlaps prelude issue + list build.
// Hazards: prelude is all block-private/read-only; sppo WRITE, Wt gather,
// flags/trace reads stay after the wait (anti-deps preserved); epilogue
// adds the final fsy2>=200 poll the old loop-end barrier provided.

#define T_STEPS 200
#define BATCH   256
#define INQ     784
#define NOUT    400
#define NP      512
#define GRID    256
#define NTHR    512
#define IMSZ    200704           // 256*784

// ws layout (float offsets)
#define OFF_WT    0            // Wt [785][512] (row 784 = zero pad for gather)
#define OFF_SYN   401920       // syn [256][512]         (block-private)
#define OFF_MEM   532992       // mem [256][512]         (block-private)
#define OFF_SPPO  664064       // interleaved (spk,post): [256][1024]  (sc1)
#define OFF_TRA   926208       // trA [256][784]         (sc1)
#define OFF_TRB   1126912      // trB [256][784]         (sc1)
#define OFF_WIN   1327616      // int win[256]           (block-private)
#define OFF_FLAGS 1327872      // u32 flags[256]         (sc1, any-spike per t)
#define OFF_BAR   1328128      // u32 bar[4096]: hierarchical barrier (prologue)
#define OFF_FSY   1332224      // u32 flagS[256*16]: per-block P1-done flags
#define OFF_FSY2  1336320      // u32 flagE[256*16]: per-block epoch-done flags
#define WS_FLOATS 1340416

typedef unsigned long long ull;

// ---- agent-coherent (sc1) access helpers ----
__device__ __forceinline__ float ld_coh(const float* p) {
  return __hip_atomic_load(p, __ATOMIC_RELAXED, __HIP_MEMORY_SCOPE_AGENT);
}
__device__ __forceinline__ float2 ld_coh2(const float* p) {
  union { ull u; float2 f; } c;
  c.u = __hip_atomic_load((const ull*)p, __ATOMIC_RELAXED, __HIP_MEMORY_SCOPE_AGENT);
  return c.f;
}
__device__ __forceinline__ unsigned ld_cohu(const unsigned* p) {
  return __hip_atomic_load(p, __ATOMIC_RELAXED, __HIP_MEMORY_SCOPE_AGENT);
}
__device__ __forceinline__ void st_coh(float* p, float v) {
  __hip_atomic_store(p, v, __ATOMIC_RELAXED, __HIP_MEMORY_SCOPE_AGENT);
}
__device__ __forceinline__ void st_coh2(float* p, float2 v) {
  union { ull u; float2 f; } c; c.f = v;
  __hip_atomic_store((ull*)p, c.u, __ATOMIC_RELAXED, __HIP_MEMORY_SCOPE_AGENT);
}
__device__ __forceinline__ void st_cohu(unsigned* p, unsigned v) {
  __hip_atomic_store(p, v, __ATOMIC_RELAXED, __HIP_MEMORY_SCOPE_AGENT);
}

__device__ __forceinline__ void gl_lds16(const float* g, float* l) {       // cached
  __builtin_amdgcn_global_load_lds(
      (const __attribute__((address_space(1))) void*)g,
      (__attribute__((address_space(3))) void*)l, 16, 0, 0);
}
__device__ __forceinline__ void gl_lds16c(const float* g, float* l) {      // sc1
  __builtin_amdgcn_global_load_lds(
      (const __attribute__((address_space(1))) void*)g,
      (__attribute__((address_space(3))) void*)l, 16, 0, 0x10);
}

// Hierarchical fence-free grid barrier — used once in the prologue.
__device__ __forceinline__ void gbar(unsigned* bar, unsigned k, int blk) {
  __syncthreads();
  if (threadIdx.x == 0) {
    const int g = blk >> 3;
    unsigned* rgen = bar + 32 * 64 + 32;
    unsigned a = __hip_atomic_fetch_add(bar + g * 64, 1u, __ATOMIC_RELAXED,
                                        __HIP_MEMORY_SCOPE_AGENT);
    if (a + 1u == k * 8u) {
      unsigned r = __hip_atomic_fetch_add(bar + 32 * 64, 1u, __ATOMIC_RELAXED,
                                          __HIP_MEMORY_SCOPE_AGENT);
      if (r + 1u == k * 32u)
        __hip_atomic_store(rgen, k, __ATOMIC_RELAXED, __HIP_MEMORY_SCOPE_AGENT);
    }
    while (__hip_atomic_load(rgen, __ATOMIC_RELAXED,
                             __HIP_MEMORY_SCOPE_AGENT) < k)
      __builtin_amdgcn_s_sleep(1);
  }
  __syncthreads();
}

__device__ __forceinline__ float clip01(float x) {
  return fminf(fmaxf(x, 0.0f), 1.0f);
}

__global__ void __launch_bounds__(NTHR) snn_kernel(
    const float* __restrict__ img,   // [200][256][784]
    const float* __restrict__ Win,   // [400][784]
    float* __restrict__ out,         // mem_rec | spk_rec | W_final
    float* ws)
{
  float* Wt    = ws + OFF_WT;
  float* syn   = ws + OFF_SYN;
  float* mem   = ws + OFF_MEM;
  float* sppo  = ws + OFF_SPPO;
  float* trA   = ws + OFF_TRA;
  float* trB   = ws + OFF_TRB;
  int*   win   = (int*)(ws + OFF_WIN);
  unsigned* flags = (unsigned*)(ws + OFF_FLAGS);
  unsigned* bar   = (unsigned*)(ws + OFF_BAR);
  unsigned* fsy   = (unsigned*)(ws + OFF_FSY);
  unsigned* fsy2  = (unsigned*)(ws + OFF_FSY2);

  float* mem_rec = out;
  float* spk_rec = out + (size_t)T_STEPS * BATCH * NOUT;
  float* Wout    = out + (size_t)2 * T_STEPS * BATCH * NOUT;

  const int tid = threadIdx.x;
  const int blk = blockIdx.x;
  const int wv = tid >> 6, ln = tid & 63;
  unsigned bt = 0;

  __shared__ int   s_list[2][800];
  __shared__ int   s_cnt2[2];
  __shared__ int   s_red8[8];
  __shared__ float stg[3][6144];      // [buf][tr 2048 | img 2048 | sppo 2048]

  // Single-wave (wave 7) ordered active-index compaction, no block syncs.
  auto build_list_w7 = [&](int tt, int slot) {
    const float* row = img + (size_t)tt * IMSZ + (size_t)blk * INQ;
    float v[13];
    #pragma unroll
    for (int c = 0; c < 13; ++c) {
      int i = c * 64 + ln;
      v[c] = row[(i < INQ) ? i : (INQ - 1)];
    }
    ull m[13];
    #pragma unroll
    for (int c = 0; c < 13; ++c) {
      int i = c * 64 + ln;
      m[c] = __ballot((i < INQ) && (v[c] != 0.0f));
    }
    int base = 0;
    #pragma unroll
    for (int c = 0; c < 13; ++c) {
      if ((m[c] >> ln) & 1ull)
        s_list[slot][base + (int)__popcll(m[c] & ((1ull << ln) - 1ull))] =
            c * 64 + ln;
      base += (int)__popcll(m[c]);
    }
    int cr = (base + 15) & ~15;
    if (cr < 48) cr = 48;
    if (ln < cr - base) s_list[slot][base + ln] = 784;   // zero-row sentinel
    if (ln == 0) s_cnt2[slot] = cr;
  };

  // ---- prologue: Wt[i][n] = Win[n][i]; list(0) ----
  for (int e = blk * NTHR + tid; e < NOUT * INQ; e += GRID * NTHR) {
    int n = e / INQ, i = e % INQ;
    st_coh(Wt + (size_t)i * NP + n, Win[e]);
  }
  if (wv == 7) build_list_w7(0, 0);
  ++bt; gbar(bar, bt, blk);

  for (int t = 0; t < T_STEPS; ++t) {
    float* trC = (t & 1) ? trB : trA;   // pre_traces[t]
    float* trN = (t & 1) ? trA : trB;   // pre_traces[t+1]
    const int slot = t & 1;

    // ---- P1 prelude: block-private / read-only, issued BEFORE epoch wait --
    float2 sp = make_float2(0.f, 0.f);
    float sv = 0.f, mv = 0.f;
    const size_t sidx = (size_t)blk * NP + tid;
    if (wv < 7 && tid < NOUT) {
      sp = ld_coh2(sppo + (size_t)blk * 1024 + 2 * tid);   // own row (P1(t-1))
      sv = syn[sidx];                                      // block-private
      mv = mem[sidx];
    }
    if (wv == 7 && t + 1 < T_STEPS)
      build_list_w7(t + 1, (t + 1) & 1);                   // read-only img

    // ---- epoch wait (arrive was published at end of previous iteration) --
    if (t > 0 && tid < 256) {
      while (ld_cohu(fsy2 + tid * 16) < (unsigned)t)
        __builtin_amdgcn_s_sleep(1);
    }
    __syncthreads();

    // ================= phase 1: block b = batch row (gather + state) ========
    {
      const int b = blk;
      const int cnt = s_cnt2[slot];
      const int anyPrev = (t > 0)
          ? (int)__hip_atomic_load(&flags[t - 1], __ATOMIC_RELAXED, __HIP_MEMORY_SCOPE_AGENT)
          : 0;
      const int wPrev = win[b];
      int localmin = 0x7fffffff;

      if (wv < 7 && tid < NOUT) {
        const int n = tid;                 // 1 neuron per thread
        float svv = sv;
        if (anyPrev && n != wPrev) svv -= 0.1f;
        float c0 = 0.f;
        const int* lrow = s_list[slot];
        {
          // 48 coherent loads in flight (lists padded to >=48; pads add 0)
          float q[48];
          #pragma unroll
          for (int u = 0; u < 48; ++u)
            q[u] = ld_coh(Wt + (size_t)lrow[u] * NP + n);
          #pragma unroll
          for (int u = 0; u < 48; ++u) c0 += q[u];
        }
        for (int j = 48; j < cnt; j += 16) {   // rare tail (cnt > 48)
          float q0  = ld_coh(Wt + (size_t)lrow[j+0]  * NP + n);
          float q1  = ld_coh(Wt + (size_t)lrow[j+1]  * NP + n);
          float q2  = ld_coh(Wt + (size_t)lrow[j+2]  * NP + n);
          float q3  = ld_coh(Wt + (size_t)lrow[j+3]  * NP + n);
          float q4  = ld_coh(Wt + (size_t)lrow[j+4]  * NP + n);
          float q5  = ld_coh(Wt + (size_t)lrow[j+5]  * NP + n);
          float q6  = ld_coh(Wt + (size_t)lrow[j+6]  * NP + n);
          float q7  = ld_coh(Wt + (size_t)lrow[j+7]  * NP + n);
          float q8  = ld_coh(Wt + (size_t)lrow[j+8]  * NP + n);
          float q9  = ld_coh(Wt + (size_t)lrow[j+9]  * NP + n);
          float q10 = ld_coh(Wt + (size_t)lrow[j+10] * NP + n);
          float q11 = ld_coh(Wt + (size_t)lrow[j+11] * NP + n);
          float q12 = ld_coh(Wt + (size_t)lrow[j+12] * NP + n);
          float q13 = ld_coh(Wt + (size_t)lrow[j+13] * NP + n);
          float q14 = ld_coh(Wt + (size_t)lrow[j+14] * NP + n);
          float q15 = ld_coh(Wt + (size_t)lrow[j+15] * NP + n);
          c0 += q0;  c0 += q1;  c0 += q2;  c0 += q3;
          c0 += q4;  c0 += q5;  c0 += q6;  c0 += q7;
          c0 += q8;  c0 += q9;  c0 += q10; c0 += q11;
          c0 += q12; c0 += q13; c0 += q14; c0 += q15;
        }
        float syn0 = fmaf(0.9f, svv, c0);
        float r0 = (mv > 1.0f) ? 1.0f : 0.0f;
        float m0 = fmaf(0.8f, mv, syn0) - r0;
        float s0 = (m0 > 1.0f) ? 1.0f : 0.0f;
        syn[sidx] = syn0;
        mem[sidx] = m0;
        float p0 = fmaf(0.9f, sp.y, s0);
        st_coh2(sppo + (size_t)b * 1024 + 2 * n, make_float2(s0, p0));
        const size_t ridx = (size_t)t * BATCH * NOUT + (size_t)b * NOUT + n;
        mem_rec[ridx] = m0;
        spk_rec[ridx] = s0;
        if (s0 != 0.f) localmin = n;
      }
      if (wv < 7) {
        int v = localmin;
        #pragma unroll
        for (int s = 1; s < 64; s <<= 1) v = min(v, __shfl_xor(v, s));
        if (ln == 0) s_red8[wv] = v;
      }
      __syncthreads();   // drains each wave's vmcnt -> sppo stores visible
      if (tid == 0) {
        int w = s_red8[0];
        #pragma unroll
        for (int q = 1; q < 7; ++q) w = min(w, s_red8[q]);
        win[b] = (w == 0x7fffffff) ? 0 : w;
        if (w != 0x7fffffff)
          __hip_atomic_fetch_or(&flags[t], 1u, __ATOMIC_RELAXED, __HIP_MEMORY_SCOPE_AGENT);
        st_cohu(fsy + blk * 16, (unsigned)(t + 1));   // publish P1(t) done
      }
    }

    // ========== phase-2 epoch: hoisted trace loads issued FIRST =============
    const float* imrow  = img + (size_t)t * IMSZ + (size_t)blk * INQ;
    const float* trCrow = trC + (size_t)blk * INQ;
    float*       trNrow = trN + (size_t)blk * INQ;
    const bool hasTr = (tid * 2 < INQ);            // 392 of 512 threads, 1 iter
    float2 tro = make_float2(0.f, 0.f), tiv = tro;
    if (hasTr) {
      tro = ld_coh2(trCrow + tid * 2);
      tiv = *(const float2*)(imrow + tid * 2);
    }

    // ================= phase 2: STDP weight update (LDS-staged) =============
    // R25 chunk loop with staggered flag wait; lane-major b128 combine.
    if (blk < 169) {
      const int bi = blk / 13, bn = blk % 13;
      const int ib0 = bi * 64, nb0 = bn * 32;
      const int brow0 = wv * 4 + (ln >> 4);
      int icol = ib0 + (ln & 15) * 4;
      if (icol > INQ - 4) icol = INQ - 4;         // clamp (garbage, discarded)
      const int scol = 2 * nb0 + ((ln & 15) ^ ((ln >> 4) & 1)) * 4;  // swizzled src
      const float* imgt = img + (size_t)t * BATCH * INQ;

      const int h  = ln >> 5;
      const int il = (ln & 31) >> 2;
      const int nl = ln & 3;
      const int wb = wv * 256;                    // wave slot base (floats)

      // ---- hoisted Wt RMW loads (issued before the flag-wait) ----
      const int cc = tid & 31;
      const int kb = (tid >> 5) * 4;
      const int iiO = kb >> 3, j0 = kb & 7;
      const int ilO = cc >> 2, nlO = cc & 3;
      const int i_loc = (iiO < 4) ? (ilO * 4 + iiO) : (32 + ilO * 4 + (iiO - 4));
      const int iO = ib0 + i_loc;
      const int nO = nb0 + nlO * 8 + j0;
      const bool okO = (nO < NOUT) && (iO < INQ);
      float2 wA = make_float2(0.f, 0.f), wB = wA;
      if (okO) {
        wA = ld_coh2(Wt + (size_t)iO * NP + nO);
        wB = ld_coh2(Wt + (size_t)iO * NP + nO + 2);
      }

      #define STG(c, buf) {                                                     \
        int br = (c) * 32 + brow0;                                              \
        float* dst = &stg[buf][wb];                                             \
        gl_lds16c(trC  + (size_t)br * INQ  + icol, dst);                        \
        gl_lds16 (imgt + (size_t)br * INQ  + icol, dst + 2048);                 \
        gl_lds16c(sppo + (size_t)br * 1024 + scol, dst + 4096);                 \
      }

      // ---- flag-wait part 1: producers of chunk-0/1 rows (b 0..63) ----
      if (tid < 64) {
        while (ld_cohu(fsy + tid * 16) < (unsigned)(t + 1))
          __builtin_amdgcn_s_sleep(1);
      }
      __syncthreads();
      // stage chunks 0,1 now; latency overlaps the remaining producer tail
      STG(0, 0);
      STG(1, 1);
      // ---- flag-wait part 2: remaining producers (b 64..255) ----
      if (tid >= 64 && tid < 256) {
        while (ld_cohu(fsy + tid * 16) < (unsigned)(t + 1))
          __builtin_amdgcn_s_sleep(1);
      }
      __syncthreads();

      float a[8][8] = {};                         // (8i,8n); b = c*32+wv*4+2qr+h

      for (int c = 0; c < 8; ++c) {
        const int buf = c % 3;
        if (c + 2 < 8) {
          STG(c + 2, (c + 2) % 3);
          __builtin_amdgcn_s_waitcnt(0x0F76);     // vmcnt(6): chunk c landed
        } else if (c == 6) {
          __builtin_amdgcn_s_waitcnt(0x0F73);     // vmcnt(3)
        } else {
          __builtin_amdgcn_s_waitcnt(0x0F70);     // vmcnt(0)
        }
        #pragma unroll
        for (int qr = 0; qr < 2; ++qr) {          // own rows of parity h, asc
          const int r  = 2 * qr + h;
          const int rb = wb + r * 64;
          const float4 t0 = *(const float4*)&stg[buf][rb + il * 4];
          const float4 t1 = *(const float4*)&stg[buf][rb + 32 + il * 4];
          const float4 g0 = *(const float4*)&stg[buf][2048 + rb + il * 4];
          const float4 g1 = *(const float4*)&stg[buf][2048 + rb + 32 + il * 4];
          // sppo source chunk nl*4+qs lives at LDS chunk (nl*4+qs)^h
          const int sb = 4096 + rb;
          const float4 s0 = *(const float4*)&stg[buf][sb + (((nl * 4 + 0) ^ h) << 2)];
          const float4 s1 = *(const float4*)&stg[buf][sb + (((nl * 4 + 1) ^ h) << 2)];
          const float4 s2 = *(const float4*)&stg[buf][sb + (((nl * 4 + 2) ^ h) << 2)];
          const float4 s3 = *(const float4*)&stg[buf][sb + (((nl * 4 + 3) ^ h) << 2)];
          const float tv[8] = { t0.x, t0.y, t0.z, t0.w, t1.x, t1.y, t1.z, t1.w };
          const float gv[8] = { g0.x, g0.y, g0.z, g0.w, g1.x, g1.y, g1.z, g1.w };
          const float ap[8] = { 1e-3f * s0.x, 1e-3f * s0.z, 1e-3f * s1.x, 1e-3f * s1.z,
                                1e-3f * s2.x, 1e-3f * s2.z, 1e-3f * s3.x, 1e-3f * s3.z };
          const float am[8] = { 1e-3f * s0.y, 1e-3f * s0.w, 1e-3f * s1.y, 1e-3f * s1.w,
                                1e-3f * s2.y, 1e-3f * s2.w, 1e-3f * s3.y, 1e-3f * s3.w };
          #pragma unroll
          for (int ii = 0; ii < 8; ++ii)
            #pragma unroll
            for (int j = 0; j < 8; ++j)
              a[ii][j] = fmaf(tv[ii], ap[j], fmaf(gv[ii], -am[j], a[ii][j]));
        }
      }
      #undef STG

      __syncthreads();                            // all waves done with stg

      // ---- combine: part[w'][lane][k] (stride 68, 16-B aligned), k contig --
      float* part = &stg[0][0];
      float dsum[4];

      if (wv < 4) {
        float* wp = part + wv * 4352 + ln * 68;
        #pragma unroll
        for (int ii = 0; ii < 8; ++ii) {
          *(float4*)(wp + ii * 8) =
              make_float4(a[ii][0], a[ii][1], a[ii][2], a[ii][3]);
          *(float4*)(wp + ii * 8 + 4) =
              make_float4(a[ii][4], a[ii][5], a[ii][6], a[ii][7]);
        }
      }
      __syncthreads();
      {
        const float4 f0 = *(const float4*)(part + 0 * 4352 + cc * 68 + kb);
        const float4 e0 = *(const float4*)(part + 0 * 4352 + (cc + 32) * 68 + kb);
        const float4 f1 = *(const float4*)(part + 1 * 4352 + cc * 68 + kb);
        const float4 e1 = *(const float4*)(part + 1 * 4352 + (cc + 32) * 68 + kb);
        const float4 f2 = *(const float4*)(part + 2 * 4352 + cc * 68 + kb);
        const float4 e2 = *(const float4*)(part + 2 * 4352 + (cc + 32) * 68 + kb);
        const float4 f3 = *(const float4*)(part + 3 * 4352 + cc * 68 + kb);
        const float4 e3 = *(const float4*)(part + 3 * 4352 + (cc + 32) * 68 + kb);
        dsum[0] = (((f0.x + e0.x) + (f1.x + e1.x)) + (f2.x + e2.x)) + (f3.x + e3.x);
        dsum[1] = (((f0.y + e0.y) + (f1.y + e1.y)) + (f2.y + e2.y)) + (f3.y + e3.y);
        dsum[2] = (((f0.z + e0.z) + (f1.z + e1.z)) + (f2.z + e2.z)) + (f3.z + e3.z);
        dsum[3] = (((f0.w + e0.w) + (f1.w + e1.w)) + (f2.w + e2.w)) + (f3.w + e3.w);
      }
      __syncthreads();
      if (wv >= 4) {
        float* wp = part + (wv - 4) * 4352 + ln * 68;
        #pragma unroll
        for (int ii = 0; ii < 8; ++ii) {
          *(float4*)(wp + ii * 8) =
              make_float4(a[ii][0], a[ii][1], a[ii][2], a[ii][3]);
          *(float4*)(wp + ii * 8 + 4) =
              make_float4(a[ii][4], a[ii][5], a[ii][6], a[ii][7]);
        }
      }
      __syncthreads();
      {
        const float4 f0 = *(const float4*)(part + 0 * 4352 + cc * 68 + kb);
        const float4 e0 = *(const float4*)(part + 0 * 4352 + (cc + 32) * 68 + kb);
        const float4 f1 = *(const float4*)(part + 1 * 4352 + cc * 68 + kb);
        const float4 e1 = *(const float4*)(part + 1 * 4352 + (cc + 32) * 68 + kb);
        const float4 f2 = *(const float4*)(part + 2 * 4352 + cc * 68 + kb);
        const float4 e2 = *(const float4*)(part + 2 * 4352 + (cc + 32) * 68 + kb);
        const float4 f3 = *(const float4*)(part + 3 * 4352 + cc * 68 + kb);
        const float4 e3 = *(const float4*)(part + 3 * 4352 + (cc + 32) * 68 + kb);
        dsum[0] += (((f0.x + e0.x) + (f1.x + e1.x)) + (f2.x + e2.x)) + (f3.x + e3.x);
        dsum[1] += (((f0.y + e0.y) + (f1.y + e1.y)) + (f2.y + e2.y)) + (f3.y + e3.y);
        dsum[2] += (((f0.z + e0.z) + (f1.z + e1.z)) + (f2.z + e2.z)) + (f3.z + e3.z);
        dsum[3] += (((f0.w + e0.w) + (f1.w + e1.w)) + (f2.w + e2.w)) + (f3.w + e3.w);
      }

      // ---- coherent Wt RMW (loads hoisted to phase-2 top) ----
      if (okO) {
        wA.x = clip01(wA.x + dsum[0]);
        wA.y = clip01(wA.y + dsum[1]);
        st_coh2(Wt + (size_t)iO * NP + nO, wA);
        wB.x = clip01(wB.x + dsum[2]);
        wB.y = clip01(wB.y + dsum[3]);
        st_coh2(Wt + (size_t)iO * NP + nO + 2, wB);
      }
    }

    // ---- all blocks: trace store (loads hoisted above) ----
    if (hasTr)
      st_coh2(trNrow + tid * 2, make_float2(fmaf(0.9f, tro.x, tiv.x),
                                            fmaf(0.9f, tro.y, tiv.y)));

    // ---- epoch ARRIVE only (wait moved to next loop-start prelude) ----
    __syncthreads();   // drains vmcnt: Wt RMW + trace + flags stores visible
    if (tid == 0) st_cohu(fsy2 + blk * 16, (unsigned)(t + 1));
  }

  // ---- final epoch wait, then W_out[n][i] = Wt[i][n] ----
  if (tid < 256) {
    while (ld_cohu(fsy2 + tid * 16) < (unsigned)T_STEPS)
      __builtin_amdgcn_s_sleep(1);
  }
  __syncthreads();
  for (int e = blk * NTHR + tid; e < NOUT * INQ; e += GRID * NTHR) {
    int n = e / INQ, i = e % INQ;
    Wout[e] = ld_coh(Wt + (size_t)i * NP + n);
  }
}

extern "C" void kernel_launch(void* const* d_in, const int* in_sizes, int n_in,
                              void* d_out, int out_size, void* d_ws, size_t ws_size,
                              hipStream_t stream) {
  const float* img = (const float*)d_in[0];
  const float* W   = (const float*)d_in[1];
  float* out = (float*)d_out;
  float* ws  = (float*)d_ws;

  hipMemsetAsync(d_ws, 0, (size_t)WS_FLOATS * sizeof(float), stream);

  void* args[] = { (void*)&img, (void*)&W, (void*)&out, (void*)&ws };
  hipLaunchCooperativeKernel((const void*)snn_kernel, dim3(GRID), dim3(NTHR),
                             args, 0, stream);
}

// Round 26
// 3507.781 us; speedup vs baseline: 1.0479x; 1.0479x over previous
//
#include <hip/hip_runtime.h>

// SNN-MNIST forward + STDP, MI355X persistent cooperative kernel.
// Round 30 = REVERT to Round 28 (best verified: 3540 us PASS, 2.12x over
// the session-start 7514 us). R29's loop-boundary epoch-barrier split
// REGRESSED (-4%): moving wave-7's list build before the epoch wait's
// __syncthreads serialized it into the critical path (in R28 it hid
// under the P1 gather). Kernel is at a distributed-latency plateau:
// HBM 14%, VALU 27%, conflicts 0 — no single term >= 3% remains.
// Structure: producer-flag sync (no tree barriers in loop), staggered
// flag wait, barrier-free 3-buffer chunk loop with counted vmcnt,
// (8i,8n) lane tile + both-sides sppo XOR swizzle, lane-major b128
// combine, hoisted Wt RMW + trace loads, wave-7 concurrent list build.

#define T_STEPS 200
#define BATCH   256
#define INQ     784
#define NOUT    400
#define NP      512
#define GRID    256
#define NTHR    512
#define IMSZ    200704           // 256*784

// ws layout (float offsets)
#define OFF_WT    0            // Wt [785][512] (row 784 = zero pad for gather)
#define OFF_SYN   401920       // syn [256][512]         (block-private)
#define OFF_MEM   532992       // mem [256][512]         (block-private)
#define OFF_SPPO  664064       // interleaved (spk,post): [256][1024]  (sc1)
#define OFF_TRA   926208       // trA [256][784]         (sc1)
#define OFF_TRB   1126912      // trB [256][784]         (sc1)
#define OFF_WIN   1327616      // int win[256]           (block-private)
#define OFF_FLAGS 1327872      // u32 flags[256]         (sc1, any-spike per t)
#define OFF_BAR   1328128      // u32 bar[4096]: hierarchical barrier (prologue)
#define OFF_FSY   1332224      // u32 flagS[256*16]: per-block P1-done flags
#define OFF_FSY2  1336320      // u32 flagE[256*16]: per-block epoch-done flags
#define WS_FLOATS 1340416

typedef unsigned long long ull;

// ---- agent-coherent (sc1) access helpers ----
__device__ __forceinline__ float ld_coh(const float* p) {
  return __hip_atomic_load(p, __ATOMIC_RELAXED, __HIP_MEMORY_SCOPE_AGENT);
}
__device__ __forceinline__ float2 ld_coh2(const float* p) {
  union { ull u; float2 f; } c;
  c.u = __hip_atomic_load((const ull*)p, __ATOMIC_RELAXED, __HIP_MEMORY_SCOPE_AGENT);
  return c.f;
}
__device__ __forceinline__ unsigned ld_cohu(const unsigned* p) {
  return __hip_atomic_load(p, __ATOMIC_RELAXED, __HIP_MEMORY_SCOPE_AGENT);
}
__device__ __forceinline__ void st_coh(float* p, float v) {
  __hip_atomic_store(p, v, __ATOMIC_RELAXED, __HIP_MEMORY_SCOPE_AGENT);
}
__device__ __forceinline__ void st_coh2(float* p, float2 v) {
  union { ull u; float2 f; } c; c.f = v;
  __hip_atomic_store((ull*)p, c.u, __ATOMIC_RELAXED, __HIP_MEMORY_SCOPE_AGENT);
}
__device__ __forceinline__ void st_cohu(unsigned* p, unsigned v) {
  __hip_atomic_store(p, v, __ATOMIC_RELAXED, __HIP_MEMORY_SCOPE_AGENT);
}

__device__ __forceinline__ void gl_lds16(const float* g, float* l) {       // cached
  __builtin_amdgcn_global_load_lds(
      (const __attribute__((address_space(1))) void*)g,
      (__attribute__((address_space(3))) void*)l, 16, 0, 0);
}
__device__ __forceinline__ void gl_lds16c(const float* g, float* l) {      // sc1
  __builtin_amdgcn_global_load_lds(
      (const __attribute__((address_space(1))) void*)g,
      (__attribute__((address_space(3))) void*)l, 16, 0, 0x10);
}

// Hierarchical fence-free grid barrier — used once in the prologue.
__device__ __forceinline__ void gbar(unsigned* bar, unsigned k, int blk) {
  __syncthreads();
  if (threadIdx.x == 0) {
    const int g = blk >> 3;
    unsigned* rgen = bar + 32 * 64 + 32;
    unsigned a = __hip_atomic_fetch_add(bar + g * 64, 1u, __ATOMIC_RELAXED,
                                        __HIP_MEMORY_SCOPE_AGENT);
    if (a + 1u == k * 8u) {
      unsigned r = __hip_atomic_fetch_add(bar + 32 * 64, 1u, __ATOMIC_RELAXED,
                                          __HIP_MEMORY_SCOPE_AGENT);
      if (r + 1u == k * 32u)
        __hip_atomic_store(rgen, k, __ATOMIC_RELAXED, __HIP_MEMORY_SCOPE_AGENT);
    }
    while (__hip_atomic_load(rgen, __ATOMIC_RELAXED,
                             __HIP_MEMORY_SCOPE_AGENT) < k)
      __builtin_amdgcn_s_sleep(1);
  }
  __syncthreads();
}

__device__ __forceinline__ float clip01(float x) {
  return fminf(fmaxf(x, 0.0f), 1.0f);
}

__global__ void __launch_bounds__(NTHR) snn_kernel(
    const float* __restrict__ img,   // [200][256][784]
    const float* __restrict__ Win,   // [400][784]
    float* __restrict__ out,         // mem_rec | spk_rec | W_final
    float* ws)
{
  float* Wt    = ws + OFF_WT;
  float* syn   = ws + OFF_SYN;
  float* mem   = ws + OFF_MEM;
  float* sppo  = ws + OFF_SPPO;
  float* trA   = ws + OFF_TRA;
  float* trB   = ws + OFF_TRB;
  int*   win   = (int*)(ws + OFF_WIN);
  unsigned* flags = (unsigned*)(ws + OFF_FLAGS);
  unsigned* bar   = (unsigned*)(ws + OFF_BAR);
  unsigned* fsy   = (unsigned*)(ws + OFF_FSY);
  unsigned* fsy2  = (unsigned*)(ws + OFF_FSY2);

  float* mem_rec = out;
  float* spk_rec = out + (size_t)T_STEPS * BATCH * NOUT;
  float* Wout    = out + (size_t)2 * T_STEPS * BATCH * NOUT;

  const int tid = threadIdx.x;
  const int blk = blockIdx.x;
  const int wv = tid >> 6, ln = tid & 63;
  unsigned bt = 0;

  __shared__ int   s_list[2][800];
  __shared__ int   s_cnt2[2];
  __shared__ int   s_red8[8];
  __shared__ float stg[3][6144];      // [buf][tr 2048 | img 2048 | sppo 2048]

  // Single-wave (wave 7) ordered active-index compaction, no block syncs.
  auto build_list_w7 = [&](int tt, int slot) {
    const float* row = img + (size_t)tt * IMSZ + (size_t)blk * INQ;
    float v[13];
    #pragma unroll
    for (int c = 0; c < 13; ++c) {
      int i = c * 64 + ln;
      v[c] = row[(i < INQ) ? i : (INQ - 1)];
    }
    ull m[13];
    #pragma unroll
    for (int c = 0; c < 13; ++c) {
      int i = c * 64 + ln;
      m[c] = __ballot((i < INQ) && (v[c] != 0.0f));
    }
    int base = 0;
    #pragma unroll
    for (int c = 0; c < 13; ++c) {
      if ((m[c] >> ln) & 1ull)
        s_list[slot][base + (int)__popcll(m[c] & ((1ull << ln) - 1ull))] =
            c * 64 + ln;
      base += (int)__popcll(m[c]);
    }
    int cr = (base + 15) & ~15;
    if (cr < 48) cr = 48;
    if (ln < cr - base) s_list[slot][base + ln] = 784;   // zero-row sentinel
    if (ln == 0) s_cnt2[slot] = cr;
  };

  // ---- prologue: Wt[i][n] = Win[n][i]; list(0) ----
  for (int e = blk * NTHR + tid; e < NOUT * INQ; e += GRID * NTHR) {
    int n = e / INQ, i = e % INQ;
    st_coh(Wt + (size_t)i * NP + n, Win[e]);
  }
  if (wv == 7) build_list_w7(0, 0);
  ++bt; gbar(bar, bt, blk);

  for (int t = 0; t < T_STEPS; ++t) {
    float* trC = (t & 1) ? trB : trA;   // pre_traces[t]
    float* trN = (t & 1) ? trA : trB;   // pre_traces[t+1]

    // ================= phase 1: block b = batch row (gather + state) ========
    // Waves 0-6: 1 neuron/thread gather+state. Wave 7: builds list(t+1).
    {
      const int b = blk;
      const int slot = t & 1;
      const int cnt = s_cnt2[slot];
      const int anyPrev = (t > 0)
          ? (int)__hip_atomic_load(&flags[t - 1], __ATOMIC_RELAXED, __HIP_MEMORY_SCOPE_AGENT)
          : 0;
      const int wPrev = win[b];
      int localmin = 0x7fffffff;

      if (wv == 7) {
        if (t + 1 < T_STEPS) build_list_w7(t + 1, (t + 1) & 1);
      } else if (tid < NOUT) {
        const int n = tid;                 // 1 neuron per thread
        const size_t sidx = (size_t)b * NP + n;
        // hoisted sppo load (latency hidden under gather)
        float2 sp = ld_coh2(sppo + (size_t)b * 1024 + 2 * n);
        float sv = syn[sidx];
        if (anyPrev && n != wPrev) sv -= 0.1f;
        float c0 = 0.f;
        const int* lrow = s_list[slot];
        {
          // 48 coherent loads in flight (lists padded to >=48; pads add 0)
          float q[48];
          #pragma unroll
          for (int u = 0; u < 48; ++u)
            q[u] = ld_coh(Wt + (size_t)lrow[u] * NP + n);
          #pragma unroll
          for (int u = 0; u < 48; ++u) c0 += q[u];
        }
        for (int j = 48; j < cnt; j += 16) {   // rare tail (cnt > 48)
          float q0  = ld_coh(Wt + (size_t)lrow[j+0]  * NP + n);
          float q1  = ld_coh(Wt + (size_t)lrow[j+1]  * NP + n);
          float q2  = ld_coh(Wt + (size_t)lrow[j+2]  * NP + n);
          float q3  = ld_coh(Wt + (size_t)lrow[j+3]  * NP + n);
          float q4  = ld_coh(Wt + (size_t)lrow[j+4]  * NP + n);
          float q5  = ld_coh(Wt + (size_t)lrow[j+5]  * NP + n);
          float q6  = ld_coh(Wt + (size_t)lrow[j+6]  * NP + n);
          float q7  = ld_coh(Wt + (size_t)lrow[j+7]  * NP + n);
          float q8  = ld_coh(Wt + (size_t)lrow[j+8]  * NP + n);
          float q9  = ld_coh(Wt + (size_t)lrow[j+9]  * NP + n);
          float q10 = ld_coh(Wt + (size_t)lrow[j+10] * NP + n);
          float q11 = ld_coh(Wt + (size_t)lrow[j+11] * NP + n);
          float q12 = ld_coh(Wt + (size_t)lrow[j+12] * NP + n);
          float q13 = ld_coh(Wt + (size_t)lrow[j+13] * NP + n);
          float q14 = ld_coh(Wt + (size_t)lrow[j+14] * NP + n);
          float q15 = ld_coh(Wt + (size_t)lrow[j+15] * NP + n);
          c0 += q0;  c0 += q1;  c0 += q2;  c0 += q3;
          c0 += q4;  c0 += q5;  c0 += q6;  c0 += q7;
          c0 += q8;  c0 += q9;  c0 += q10; c0 += q11;
          c0 += q12; c0 += q13; c0 += q14; c0 += q15;
        }
        float mv = mem[sidx];
        float syn0 = fmaf(0.9f, sv, c0);
        float r0 = (mv > 1.0f) ? 1.0f : 0.0f;
        float m0 = fmaf(0.8f, mv, syn0) - r0;
        float s0 = (m0 > 1.0f) ? 1.0f : 0.0f;
        syn[sidx] = syn0;
        mem[sidx] = m0;
        float p0 = fmaf(0.9f, sp.y, s0);
        st_coh2(sppo + (size_t)b * 1024 + 2 * n, make_float2(s0, p0));
        const size_t ridx = (size_t)t * BATCH * NOUT + (size_t)b * NOUT + n;
        mem_rec[ridx] = m0;
        spk_rec[ridx] = s0;
        if (s0 != 0.f) localmin = n;
      }
      if (wv < 7) {
        int v = localmin;
        #pragma unroll
        for (int s = 1; s < 64; s <<= 1) v = min(v, __shfl_xor(v, s));
        if (ln == 0) s_red8[wv] = v;
      }
      __syncthreads();   // drains each wave's vmcnt -> sppo stores visible
      if (tid == 0) {
        int w = s_red8[0];
        #pragma unroll
        for (int q = 1; q < 7; ++q) w = min(w, s_red8[q]);
        win[b] = (w == 0x7fffffff) ? 0 : w;
        if (w != 0x7fffffff)
          __hip_atomic_fetch_or(&flags[t], 1u, __ATOMIC_RELAXED, __HIP_MEMORY_SCOPE_AGENT);
        st_cohu(fsy + blk * 16, (unsigned)(t + 1));   // publish P1(t) done
      }
    }
    // (bar1 deleted: P2 waits on producer flags instead)

    // ========== phase-2 epoch: hoisted trace loads issued FIRST =============
    const float* imrow  = img + (size_t)t * IMSZ + (size_t)blk * INQ;
    const float* trCrow = trC + (size_t)blk * INQ;
    float*       trNrow = trN + (size_t)blk * INQ;
    const bool hasTr = (tid * 2 < INQ);            // 392 of 512 threads, 1 iter
    float2 tro = make_float2(0.f, 0.f), tiv = tro;
    if (hasTr) {
      tro = ld_coh2(trCrow + tid * 2);
      tiv = *(const float2*)(imrow + tid * 2);
    }

    // ================= phase 2: STDP weight update (LDS-staged) =============
    // R17 chunk loop with staggered flag wait; lane-major b128 combine.
    if (blk < 169) {
      const int bi = blk / 13, bn = blk % 13;
      const int ib0 = bi * 64, nb0 = bn * 32;
      const int brow0 = wv * 4 + (ln >> 4);
      int icol = ib0 + (ln & 15) * 4;
      if (icol > INQ - 4) icol = INQ - 4;         // clamp (garbage, discarded)
      const int scol = 2 * nb0 + ((ln & 15) ^ ((ln >> 4) & 1)) * 4;  // swizzled src
      const float* imgt = img + (size_t)t * BATCH * INQ;

      const int h  = ln >> 5;
      const int il = (ln & 31) >> 2;
      const int nl = ln & 3;
      const int wb = wv * 256;                    // wave slot base (floats)

      // ---- hoisted Wt RMW loads (issued before the flag-wait) ----
      const int cc = tid & 31;
      const int kb = (tid >> 5) * 4;
      const int iiO = kb >> 3, j0 = kb & 7;
      const int ilO = cc >> 2, nlO = cc & 3;
      const int i_loc = (iiO < 4) ? (ilO * 4 + iiO) : (32 + ilO * 4 + (iiO - 4));
      const int iO = ib0 + i_loc;
      const int nO = nb0 + nlO * 8 + j0;
      const bool okO = (nO < NOUT) && (iO < INQ);
      float2 wA = make_float2(0.f, 0.f), wB = wA;
      if (okO) {
        wA = ld_coh2(Wt + (size_t)iO * NP + nO);
        wB = ld_coh2(Wt + (size_t)iO * NP + nO + 2);
      }

      #define STG(c, buf) {                                                     \
        int br = (c) * 32 + brow0;                                              \
        float* dst = &stg[buf][wb];                                             \
        gl_lds16c(trC  + (size_t)br * INQ  + icol, dst);                        \
        gl_lds16 (imgt + (size_t)br * INQ  + icol, dst + 2048);                 \
        gl_lds16c(sppo + (size_t)br * 1024 + scol, dst + 4096);                 \
      }

      // ---- flag-wait part 1: producers of chunk-0/1 rows (b 0..63) ----
      if (tid < 64) {
        while (ld_cohu(fsy + tid * 16) < (unsigned)(t + 1))
          __builtin_amdgcn_s_sleep(1);
      }
      __syncthreads();
      // stage chunks 0,1 now; latency overlaps the remaining producer tail
      STG(0, 0);
      STG(1, 1);
      // ---- flag-wait part 2: remaining producers (b 64..255) ----
      if (tid >= 64 && tid < 256) {
        while (ld_cohu(fsy + tid * 16) < (unsigned)(t + 1))
          __builtin_amdgcn_s_sleep(1);
      }
      __syncthreads();

      float a[8][8] = {};                         // (8i,8n); b = c*32+wv*4+2qr+h

      for (int c = 0; c < 8; ++c) {
        const int buf = c % 3;
        if (c + 2 < 8) {
          STG(c + 2, (c + 2) % 3);
          __builtin_amdgcn_s_waitcnt(0x0F76);     // vmcnt(6): chunk c landed
        } else if (c == 6) {
          __builtin_amdgcn_s_waitcnt(0x0F73);     // vmcnt(3)
        } else {
          __builtin_amdgcn_s_waitcnt(0x0F70);     // vmcnt(0)
        }
        #pragma unroll
        for (int qr = 0; qr < 2; ++qr) {          // own rows of parity h, asc
          const int r  = 2 * qr + h;
          const int rb = wb + r * 64;
          const float4 t0 = *(const float4*)&stg[buf][rb + il * 4];
          const float4 t1 = *(const float4*)&stg[buf][rb + 32 + il * 4];
          const float4 g0 = *(const float4*)&stg[buf][2048 + rb + il * 4];
          const float4 g1 = *(const float4*)&stg[buf][2048 + rb + 32 + il * 4];
          // sppo source chunk nl*4+qs lives at LDS chunk (nl*4+qs)^h
          const int sb = 4096 + rb;
          const float4 s0 = *(const float4*)&stg[buf][sb + (((nl * 4 + 0) ^ h) << 2)];
          const float4 s1 = *(const float4*)&stg[buf][sb + (((nl * 4 + 1) ^ h) << 2)];
          const float4 s2 = *(const float4*)&stg[buf][sb + (((nl * 4 + 2) ^ h) << 2)];
          const float4 s3 = *(const float4*)&stg[buf][sb + (((nl * 4 + 3) ^ h) << 2)];
          const float tv[8] = { t0.x, t0.y, t0.z, t0.w, t1.x, t1.y, t1.z, t1.w };
          const float gv[8] = { g0.x, g0.y, g0.z, g0.w, g1.x, g1.y, g1.z, g1.w };
          const float ap[8] = { 1e-3f * s0.x, 1e-3f * s0.z, 1e-3f * s1.x, 1e-3f * s1.z,
                                1e-3f * s2.x, 1e-3f * s2.z, 1e-3f * s3.x, 1e-3f * s3.z };
          const float am[8] = { 1e-3f * s0.y, 1e-3f * s0.w, 1e-3f * s1.y, 1e-3f * s1.w,
                                1e-3f * s2.y, 1e-3f * s2.w, 1e-3f * s3.y, 1e-3f * s3.w };
          #pragma unroll
          for (int ii = 0; ii < 8; ++ii)
            #pragma unroll
            for (int j = 0; j < 8; ++j)
              a[ii][j] = fmaf(tv[ii], ap[j], fmaf(gv[ii], -am[j], a[ii][j]));
        }
      }
      #undef STG

      __syncthreads();                            // all waves done with stg

      // ---- combine: part[w'][lane][k] (stride 68, 16-B aligned), k contig --
      // [4][64][68] = 17408 floats (fits stg's 18432). b128 stores/loads.
      // Summation order identical to scalar version: s_w = part_w[cc] +
      // part_w[cc+32]; dsum = ((s0+s1)+s2)+s3; then += ((s4+s5)+s6)+s7.
      float* part = &stg[0][0];
      float dsum[4];

      if (wv < 4) {
        float* wp = part + wv * 4352 + ln * 68;
        #pragma unroll
        for (int ii = 0; ii < 8; ++ii) {
          *(float4*)(wp + ii * 8) =
              make_float4(a[ii][0], a[ii][1], a[ii][2], a[ii][3]);
          *(float4*)(wp + ii * 8 + 4) =
              make_float4(a[ii][4], a[ii][5], a[ii][6], a[ii][7]);
        }
      }
      __syncthreads();
      {
        const float4 f0 = *(const float4*)(part + 0 * 4352 + cc * 68 + kb);
        const float4 e0 = *(const float4*)(part + 0 * 4352 + (cc + 32) * 68 + kb);
        const float4 f1 = *(const float4*)(part + 1 * 4352 + cc * 68 + kb);
        const float4 e1 = *(const float4*)(part + 1 * 4352 + (cc + 32) * 68 + kb);
        const float4 f2 = *(const float4*)(part + 2 * 4352 + cc * 68 + kb);
        const float4 e2 = *(const float4*)(part + 2 * 4352 + (cc + 32) * 68 + kb);
        const float4 f3 = *(const float4*)(part + 3 * 4352 + cc * 68 + kb);
        const float4 e3 = *(const float4*)(part + 3 * 4352 + (cc + 32) * 68 + kb);
        dsum[0] = (((f0.x + e0.x) + (f1.x + e1.x)) + (f2.x + e2.x)) + (f3.x + e3.x);
        dsum[1] = (((f0.y + e0.y) + (f1.y + e1.y)) + (f2.y + e2.y)) + (f3.y + e3.y);
        dsum[2] = (((f0.z + e0.z) + (f1.z + e1.z)) + (f2.z + e2.z)) + (f3.z + e3.z);
        dsum[3] = (((f0.w + e0.w) + (f1.w + e1.w)) + (f2.w + e2.w)) + (f3.w + e3.w);
      }
      __syncthreads();
      if (wv >= 4) {
        float* wp = part + (wv - 4) * 4352 + ln * 68;
        #pragma unroll
        for (int ii = 0; ii < 8; ++ii) {
          *(float4*)(wp + ii * 8) =
              make_float4(a[ii][0], a[ii][1], a[ii][2], a[ii][3]);
          *(float4*)(wp + ii * 8 + 4) =
              make_float4(a[ii][4], a[ii][5], a[ii][6], a[ii][7]);
        }
      }
      __syncthreads();
      {
        const float4 f0 = *(const float4*)(part + 0 * 4352 + cc * 68 + kb);
        const float4 e0 = *(const float4*)(part + 0 * 4352 + (cc + 32) * 68 + kb);
        const float4 f1 = *(const float4*)(part + 1 * 4352 + cc * 68 + kb);
        const float4 e1 = *(const float4*)(part + 1 * 4352 + (cc + 32) * 68 + kb);
        const float4 f2 = *(const float4*)(part + 2 * 4352 + cc * 68 + kb);
        const float4 e2 = *(const float4*)(part + 2 * 4352 + (cc + 32) * 68 + kb);
        const float4 f3 = *(const float4*)(part + 3 * 4352 + cc * 68 + kb);
        const float4 e3 = *(const float4*)(part + 3 * 4352 + (cc + 32) * 68 + kb);
        dsum[0] += (((f0.x + e0.x) + (f1.x + e1.x)) + (f2.x + e2.x)) + (f3.x + e3.x);
        dsum[1] += (((f0.y + e0.y) + (f1.y + e1.y)) + (f2.y + e2.y)) + (f3.y + e3.y);
        dsum[2] += (((f0.z + e0.z) + (f1.z + e1.z)) + (f2.z + e2.z)) + (f3.z + e3.z);
        dsum[3] += (((f0.w + e0.w) + (f1.w + e1.w)) + (f2.w + e2.w)) + (f3.w + e3.w);
      }

      // ---- coherent Wt RMW (loads hoisted to phase-2 top) ----
      if (okO) {
        wA.x = clip01(wA.x + dsum[0]);
        wA.y = clip01(wA.y + dsum[1]);
        st_coh2(Wt + (size_t)iO * NP + nO, wA);
        wB.x = clip01(wB.x + dsum[2]);
        wB.y = clip01(wB.y + dsum[3]);
        st_coh2(Wt + (size_t)iO * NP + nO + 2, wB);
      }
    }

    // ---- all blocks: trace store (loads hoisted above) ----
    if (hasTr)
      st_coh2(trNrow + tid * 2, make_float2(fmaf(0.9f, tro.x, tiv.x),
                                            fmaf(0.9f, tro.y, tiv.y)));

    // ---- flat epoch barrier: publish + parallel poll ----
    __syncthreads();   // drains vmcnt: Wt RMW + trace stores visible
    if (tid == 0) st_cohu(fsy2 + blk * 16, (unsigned)(t + 1));
    if (tid < 256) {
      while (ld_cohu(fsy2 + tid * 16) < (unsigned)(t + 1))
        __builtin_amdgcn_s_sleep(1);
    }
    __syncthreads();
  }

  // ---- final: W_out[n][i] = Wt[i][n] ----
  for (int e = blk * NTHR + tid; e < NOUT * INQ; e += GRID * NTHR) {
    int n = e / INQ, i = e % INQ;
    Wout[e] = ld_coh(Wt + (size_t)i * NP + n);
  }
}

extern "C" void kernel_launch(void* const* d_in, const int* in_sizes, int n_in,
                              void* d_out, int out_size, void* d_ws, size_t ws_size,
                              hipStream_t stream) {
  const float* img = (const float*)d_in[0];
  const float* W   = (const float*)d_in[1];
  float* out = (float*)d_out;
  float* ws  = (float*)d_ws;

  hipMemsetAsync(d_ws, 0, (size_t)WS_FLOATS * sizeof(float), stream);

  void* args[] = { (void*)&img, (void*)&W, (void*)&out, (void*)&ws };
  hipLaunchCooperativeKernel((const void*)snn_kernel, dim3(GRID), dim3(NTHR),
                             args, 0, stream);
}